// Round 7
// baseline (2944.090 us; speedup 1.0000x reference)
//
#include <hip/hip_runtime.h>
#include <stdint.h>

#define TT 400
#define BB 256
#define II 256
#define HH 512
#define NG 2048  // 4*H

typedef __attribute__((ext_vector_type(8))) _Float16 half8;
typedef __attribute__((ext_vector_type(4))) float f32x4;
typedef __attribute__((ext_vector_type(4))) unsigned int u32x4;
typedef unsigned int u32;
typedef unsigned short u16;

static __device__ __forceinline__ u32 f2hbits(float f){
  union { _Float16 h; u16 u; } c; c.h = (_Float16)f; return (u32)c.u;
}

#define GLOAD16(gsrc, ldst) \
  __builtin_amdgcn_global_load_lds((const __attribute__((address_space(1))) void*)(gsrc), \
                                   (__attribute__((address_space(3))) void*)(ldst), 16, 0, 0)

// ---------------------------------------------------------------------------
// Transpose x[B][I][T] fp32 -> xT[t][b][i] fp16. Tile 32(i) x 16(t).
__global__ __launch_bounds__(256) void k_prep_x(const float* __restrict__ x,
                                                u16* __restrict__ xT){
  __shared__ float tile[32][17];
  const int bid = blockIdx.x;
  const int tb = bid % 25, ib = (bid / 25) & 7, b = bid / 200;
  const int t0 = tb * 16, i0 = ib * 32;
  const int tl = threadIdx.x & 15, il = threadIdx.x >> 4;
  tile[il][tl]      = x[(size_t)(b * II + i0 + il) * TT + t0 + tl];
  tile[il + 16][tl] = x[(size_t)(b * II + i0 + il + 16) * TT + t0 + tl];
  __syncthreads();
  const int t_l = threadIdx.x >> 4, ip = threadIdx.x & 15;
  const u32 pack = f2hbits(tile[2 * ip][t_l]) | (f2hbits(tile[2 * ip + 1][t_l]) << 16);
  *(u32*)(xT + ((size_t)(t0 + t_l) * BB + b) * II + i0 + 2 * ip) = pack;
}

// ---------------------------------------------------------------------------
// w_ih[2048][256] fp32 -> fp16.
__global__ __launch_bounds__(256) void k_prep_w(const float* __restrict__ w_ih,
                                                u16* __restrict__ Wp){
  const size_t idx = (size_t)blockIdx.x * 256 + threadIdx.x;  // 0..131071
  const float4 v = *(const float4*)(w_ih + idx * 4);
  uint2 o;
  o.x = f2hbits(v.x) | (f2hbits(v.y) << 16);
  o.y = f2hbits(v.z) | (f2hbits(v.w) << 16);
  *(uint2*)(Wp + idx * 4) = o;
}

// ---------------------------------------------------------------------------
// xg[M=102400][2048] fp16 = A[M][256] @ Wp[2048][256]^T, fp16 MFMA, K=256.
__global__ __launch_bounds__(256) void k_gemm_xg(const u16* __restrict__ A,
                                                 const u16* __restrict__ B,
                                                 _Float16* __restrict__ xg){
  __shared__ char lds[65536];
  const int tid = threadIdx.x, w = tid >> 6, lane = tid & 63;
  const int nb = blockIdx.x & 15, mb = blockIdx.x >> 4;
  const size_t m0 = (size_t)mb * 128;
  const int n0 = nb * 128;
  const int lr = lane & 15, lh = lane >> 4;

  auto stage = [&](int it, int buf){
    const size_t kb = (size_t)it * 128;
    #pragma unroll
    for (int i2 = 0; i2 < 4; ++i2){
      const int u = w * 256 + i2 * 64 + lane;
      const int r = u >> 3, s = u & 7;
      const char* g = (const char*)A + (m0 + r) * 512 + kb + ((s ^ (r & 7)) << 4);
      char* l = lds + buf * 16384 + ((w * 256 + i2 * 64) << 4);
      GLOAD16(g, l);
    }
    #pragma unroll
    for (int i2 = 0; i2 < 4; ++i2){
      const int u = w * 256 + i2 * 64 + lane;
      const int r = u >> 3, s = u & 7;
      const char* g = (const char*)B + (size_t)(n0 + r) * 512 + kb + ((s ^ (r & 7)) << 4);
      char* l = lds + 32768 + buf * 16384 + ((w * 256 + i2 * 64) << 4);
      GLOAD16(g, l);
    }
  };

  f32x4 acc[4][4];
  #pragma unroll
  for (int i = 0; i < 4; ++i)
    #pragma unroll
    for (int j = 0; j < 4; ++j){ f32x4 z = {0.f,0.f,0.f,0.f}; acc[i][j] = z; }

  const int wm = (w & 1) * 64, wn = (w >> 1) * 64;
  stage(0, 0);
  for (int it = 0; it < 4; ++it){
    const int buf = it & 1;
    if (it < 3) stage(it + 1, buf ^ 1);
    __syncthreads();
    const char* lA = lds + buf * 16384;
    const char* lB = lds + 32768 + buf * 16384;
    #pragma unroll
    for (int ks = 0; ks < 2; ++ks){
      half8 a[4], b[4];
      const int s = ks * 4 + lh;
      #pragma unroll
      for (int mt = 0; mt < 4; ++mt){
        const int r = wm + mt * 16 + lr;
        a[mt] = *(const half8*)(lA + r * 128 + ((s ^ (r & 7)) << 4));
      }
      #pragma unroll
      for (int nt = 0; nt < 4; ++nt){
        const int r = wn + nt * 16 + lr;
        b[nt] = *(const half8*)(lB + r * 128 + ((s ^ (r & 7)) << 4));
      }
      #pragma unroll
      for (int mt = 0; mt < 4; ++mt)
        #pragma unroll
        for (int nt = 0; nt < 4; ++nt)
          acc[mt][nt] = __builtin_amdgcn_mfma_f32_16x16x32_f16(a[mt], b[nt], acc[mt][nt], 0, 0, 0);
    }
    __syncthreads();
  }
  #pragma unroll
  for (int mt = 0; mt < 4; ++mt)
    #pragma unroll
    for (int nt = 0; nt < 4; ++nt)
      #pragma unroll
      for (int r = 0; r < 4; ++r){
        const size_t row = m0 + wm + mt * 16 + lh * 4 + r;
        const int col = n0 + wn + nt * 16 + lr;
        xg[row * NG + col] = (_Float16)acc[mt][nt][r];
      }
}

// ---------------------------------------------------------------------------
// Persistent recurrent kernel v6: per-wave slice staging + LDS tag-spin,
// one barrier per step, in-wave gate transpose via ds_bpermute.
// Group g = blockIdx&15 (batch rows [16g,+16)), col-WG n = blockIdx>>4
// (h-cols [32n,+32)). htag[2][256][512] u32: low16 fp16(h), high16 tag t+1.
// LDS: Wl 128KB (permuted gate rows) + hb 32KB (tagged h, single buffer).
// Slice s (h-cols [32s,+32)) staged by wave s>>1; consumers spin on LDS tags.
__global__ __launch_bounds__(512) void k_lstm(const _Float16* __restrict__ xg,
    const float* __restrict__ w_hh, const float* __restrict__ b_ih,
    const float* __restrict__ b_hh, u32* __restrict__ htag,
    float* __restrict__ out){
  extern __shared__ char lds[];
  char* Wl = lds;                 // 131072 B: [128 rows][512 fp16], 16B-unit swz ^(row&15)
  char* hb = lds + 131072;        //  32768 B: tagged u32 [16 rows][512], unit swz ^row

  const int tid = threadIdx.x, w = tid >> 6, lane = tid & 63;
  const int lr = lane & 15, lh = lane >> 4;
  const int g = blockIdx.x & 15, n = blockIdx.x >> 4;
  const int b0 = g * 16, j0 = n * 32;

  // ---- Wl load, PERMUTED: local row r -> gate row ((r>>2)&3)*512 + j0 + (r>>4)*4 + (r&3)
  for (int rep = 0; rep < 16; ++rep){
    const int u = rep * 512 + tid;        // 0..8191 units of 8 fp16
    const int row = u >> 6, u0 = u & 63;
    const int grow = ((row >> 2) & 3) * 512 + j0 + (row >> 4) * 4 + (row & 3);
    const float* src = w_hh + (size_t)grow * HH + u0 * 8;
    const float4 va = *(const float4*)src;
    const float4 vb = *(const float4*)(src + 4);
    union { _Float16 h[8]; u32x4 v; } p;
    p.h[0] = (_Float16)va.x; p.h[1] = (_Float16)va.y;
    p.h[2] = (_Float16)va.z; p.h[3] = (_Float16)va.w;
    p.h[4] = (_Float16)vb.x; p.h[5] = (_Float16)vb.y;
    p.h[6] = (_Float16)vb.z; p.h[7] = (_Float16)vb.w;
    *(u32x4*)(Wl + row * 1024 + ((u0 ^ (row & 15)) << 4)) = p.v;
  }
  // ---- hb tag clear (tag 0 < any expected tag >= 1)
  {
    u32x4 z = {0u, 0u, 0u, 0u};
    #pragma unroll
    for (int k2 = 0; k2 < 4; ++k2)
      *(u32x4*)(hb + (k2 * 512 + tid) * 16) = z;
  }

  // ---- cell ownership: lane -> (m = lane>>2, cc = lane&3), col = j0 + 4w + cc
  const int mcell = lane >> 2, cc = lane & 3;
  const int col = j0 + w * 4 + cc;
  const int sel = mcell & 3;
  float biasv[4];
  #pragma unroll
  for (int q2 = 0; q2 < 4; ++q2)
    biasv[q2] = b_ih[q2 * HH + col] + b_hh[q2 * HH + col];
  float c = 0.f;

  // ---- staging constants: wave w stages slices 2w, 2w+1; lane -> (r, c8)
  const int sr = lane >> 2, sc8 = lane & 3;
  const int s0 = 2 * w, s1 = 2 * w + 1;
  const int lbase = sr * 2048;
  const int la0 = lbase + (((s0 * 8 + sc8 * 2    ) ^ sr) << 4);
  const int la1 = lbase + (((s0 * 8 + sc8 * 2 + 1) ^ sr) << 4);
  const int lb0 = lbase + (((s1 * 8 + sc8 * 2    ) ^ sr) << 4);
  const int lb1 = lbase + (((s1 * 8 + sc8 * 2 + 1) ^ sr) << 4);
  u32* const hb32 = (u32*)hb;

  __syncthreads();

  // xg prefetch for t=0
  u32 xv0, xv1, xv2, xv3;
  {
    const _Float16* xt = xg + (size_t)(b0 + mcell) * NG + col;
    asm volatile(
      "global_load_ushort %0, %4, off\n\t"
      "global_load_ushort %1, %5, off\n\t"
      "global_load_ushort %2, %6, off\n\t"
      "global_load_ushort %3, %7, off"
      : "=&v"(xv0), "=&v"(xv1), "=&v"(xv2), "=&v"(xv3)
      : "v"(xt), "v"(xt + HH), "v"(xt + 2 * HH), "v"(xt + 3 * HH)
      : "memory");
  }

#define LDSPIN_CONSUME(KS, ACC) do { \
  const int ua_ = (KS) * 8 + lh * 2; \
  const int i0_ = (lr * 2048 + ((ua_ ^ lr) << 4)) >> 2; \
  const int i1_ = (lr * 2048 + (((ua_ + 1) ^ lr) << 4)) >> 2; \
  u32 f0,f1,f2,f3,f4,f5,f6,f7; int gg_ = 0; \
  while (true){ \
    f0 = __hip_atomic_load(hb32 + i0_ + 0, __ATOMIC_RELAXED, __HIP_MEMORY_SCOPE_WORKGROUP); \
    f1 = __hip_atomic_load(hb32 + i0_ + 1, __ATOMIC_RELAXED, __HIP_MEMORY_SCOPE_WORKGROUP); \
    f2 = __hip_atomic_load(hb32 + i0_ + 2, __ATOMIC_RELAXED, __HIP_MEMORY_SCOPE_WORKGROUP); \
    f3 = __hip_atomic_load(hb32 + i0_ + 3, __ATOMIC_RELAXED, __HIP_MEMORY_SCOPE_WORKGROUP); \
    f4 = __hip_atomic_load(hb32 + i1_ + 0, __ATOMIC_RELAXED, __HIP_MEMORY_SCOPE_WORKGROUP); \
    f5 = __hip_atomic_load(hb32 + i1_ + 1, __ATOMIC_RELAXED, __HIP_MEMORY_SCOPE_WORKGROUP); \
    f6 = __hip_atomic_load(hb32 + i1_ + 2, __ATOMIC_RELAXED, __HIP_MEMORY_SCOPE_WORKGROUP); \
    f7 = __hip_atomic_load(hb32 + i1_ + 3, __ATOMIC_RELAXED, __HIP_MEMORY_SCOPE_WORKGROUP); \
    const u32 m_ = (f0^te)|(f1^te)|(f2^te)|(f3^te)|(f4^te)|(f5^te)|(f6^te)|(f7^te); \
    if (!(m_ >> 16) || ++gg_ >= (1 << 16)) break; \
  } \
  u32x4 pk_; \
  pk_[0] = (f0 & 0xffffu) | (f1 << 16); \
  pk_[1] = (f2 & 0xffffu) | (f3 << 16); \
  pk_[2] = (f4 & 0xffffu) | (f5 << 16); \
  pk_[3] = (f6 & 0xffffu) | (f7 << 16); \
  union { u32x4 v; half8 h; } au_; au_.v = pk_; \
  const int ub_ = (KS) * 4 + lh; \
  const half8 bf_ = *(const half8*)(Wl + (w * 16 + lr) * 1024 + ((ub_ ^ lr) << 4)); \
  ACC = __builtin_amdgcn_mfma_f32_16x16x32_f16(au_.h, bf_, ACC, 0, 0, 0); \
} while (0)

  for (int t = 0; t < TT; ++t){
    float g4[4];
    if (t > 0){
      __syncthreads();   // all waves finished consuming previous hb contents
      const u32 te = ((u32)t) << 16;
      // ---- stage my 2 slices: global (sc0 sc1, tagged) -> validate -> LDS
      {
        const u32* gb = htag + (size_t)((t - 1) & 1) * 131072 + (size_t)(b0 + sr) * 512;
        const u32* pa0 = gb + s0 * 32 + sc8 * 8;
        const u32* pa1 = pa0 + 4;
        const u32* pb0 = gb + s1 * 32 + sc8 * 8;
        const u32* pb1 = pb0 + 4;
        u32x4 va0, va1, vb0, vb1;
        int pend = 15, guard = 0;
        do {
          if (pend & 1) asm volatile("global_load_dwordx4 %0, %1, off sc0 sc1"
                                     : "=&v"(va0) : "v"(pa0) : "memory");
          if (pend & 2) asm volatile("global_load_dwordx4 %0, %1, off sc0 sc1"
                                     : "=&v"(va1) : "v"(pa1) : "memory");
          if (pend & 4) asm volatile("global_load_dwordx4 %0, %1, off sc0 sc1"
                                     : "=&v"(vb0) : "v"(pb0) : "memory");
          if (pend & 8) asm volatile("global_load_dwordx4 %0, %1, off sc0 sc1"
                                     : "=&v"(vb1) : "v"(pb1) : "memory");
          asm volatile("s_waitcnt vmcnt(0)" ::: "memory");
          __builtin_amdgcn_sched_barrier(0);
          if (pend & 1){
            const u32 m_ = (va0[0]^te)|(va0[1]^te)|(va0[2]^te)|(va0[3]^te);
            if (!(m_ >> 16)){ *(u32x4*)(hb + la0) = va0; pend &= ~1; }
          }
          if (pend & 2){
            const u32 m_ = (va1[0]^te)|(va1[1]^te)|(va1[2]^te)|(va1[3]^te);
            if (!(m_ >> 16)){ *(u32x4*)(hb + la1) = va1; pend &= ~2; }
          }
          if (pend & 4){
            const u32 m_ = (vb0[0]^te)|(vb0[1]^te)|(vb0[2]^te)|(vb0[3]^te);
            if (!(m_ >> 16)){ *(u32x4*)(hb + lb0) = vb0; pend &= ~4; }
          }
          if (pend & 8){
            const u32 m_ = (vb1[0]^te)|(vb1[1]^te)|(vb1[2]^te)|(vb1[3]^te);
            if (!(m_ >> 16)){ *(u32x4*)(hb + lb1) = vb1; pend &= ~8; }
          }
          asm volatile("" ::: "memory");   // force LDS stores out promptly
        } while (pend && ++guard < (1 << 14));
      }
      // ---- consume 16 slices (own first), spin on LDS tags
      f32x4 ac0 = {0.f,0.f,0.f,0.f}, ac1 = {0.f,0.f,0.f,0.f};
      #pragma unroll
      for (int i = 0; i < 16; i += 2){
        const int ksA = (2 * w + i) & 15;
        const int ksB = (2 * w + i + 1) & 15;
        LDSPIN_CONSUME(ksA, ac0);
        LDSPIN_CONSUME(ksB, ac1);
      }
      const f32x4 acs = ac0 + ac1;
      // ---- in-wave gate transpose: lane (m,cc) gathers gate q from lane
      // (lane&48)|(q<<2)|cc, register sel=m&3. 16 bpermutes, no barrier.
      #pragma unroll
      for (int q2 = 0; q2 < 4; ++q2){
        const int addr = ((lane & 48) | (q2 << 2) | cc) << 2;
        const int r0 = __builtin_amdgcn_ds_bpermute(addr, __float_as_int(acs[0]));
        const int r1 = __builtin_amdgcn_ds_bpermute(addr, __float_as_int(acs[1]));
        const int r2 = __builtin_amdgcn_ds_bpermute(addr, __float_as_int(acs[2]));
        const int r3 = __builtin_amdgcn_ds_bpermute(addr, __float_as_int(acs[3]));
        const int rv = sel == 0 ? r0 : sel == 1 ? r1 : sel == 2 ? r2 : r3;
        g4[q2] = __int_as_float(rv);
      }
    } else {
      #pragma unroll
      for (int q2 = 0; q2 < 4; ++q2) g4[q2] = 0.f;
    }

    // ---- pointwise cell update (1 cell/thread)
    asm volatile("s_waitcnt vmcnt(0)" ::: "memory");
    asm volatile("" : "+v"(xv0), "+v"(xv1), "+v"(xv2), "+v"(xv3));
    {
      union { u32 u; _Float16 h[2]; } cv;
      cv.u = xv0; g4[0] += (float)cv.h[0] + biasv[0];
      cv.u = xv1; g4[1] += (float)cv.h[0] + biasv[1];
      cv.u = xv2; g4[2] += (float)cv.h[0] + biasv[2];
      cv.u = xv3; g4[3] += (float)cv.h[0] + biasv[3];
    }
    const float i_ = 1.f / (1.f + __expf(-g4[0]));
    const float f_ = 1.f / (1.f + __expf(-g4[1]));
    const float ea = __expf(-2.f * fabsf(g4[2]));
    const float g_ = __builtin_copysignf((1.f - ea) / (1.f + ea), g4[2]);
    const float o_ = 1.f / (1.f + __expf(-g4[3]));
    c = f_ * c + i_ * g_;
    const float eb = __expf(-2.f * fabsf(c));
    const float th = __builtin_copysignf((1.f - eb) / (1.f + eb), c);
    const float hn = o_ * th;

    if (t < TT - 1){
      u32* ph = htag + (size_t)(t & 1) * 131072 + (size_t)(b0 + mcell) * 512 + col;
      const u32 hv = f2hbits(hn) | ((u32)(t + 1) << 16);
      asm volatile("global_store_dword %0, %1, off sc0 sc1"
                   :: "v"(ph), "v"(hv) : "memory");
      // prefetch xg for t+1
      const _Float16* xt = xg + (size_t)(t + 1) * (BB * NG) + (size_t)(b0 + mcell) * NG + col;
      asm volatile(
        "global_load_ushort %0, %4, off\n\t"
        "global_load_ushort %1, %5, off\n\t"
        "global_load_ushort %2, %6, off\n\t"
        "global_load_ushort %3, %7, off"
        : "=&v"(xv0), "=&v"(xv1), "=&v"(xv2), "=&v"(xv3)
        : "v"(xt), "v"(xt + HH), "v"(xt + 2 * HH), "v"(xt + 3 * HH)
        : "memory");
    }
    out[(size_t)t * (BB * HH) + (size_t)(b0 + mcell) * HH + col] = c;
  }
#undef LDSPIN_CONSUME
}

// ---------------------------------------------------------------------------
extern "C" void kernel_launch(void* const* d_in, const int* in_sizes, int n_in,
                              void* d_out, int out_size, void* d_ws, size_t ws_size,
                              hipStream_t stream){
  const float* x    = (const float*)d_in[0];
  const float* w_ih = (const float*)d_in[1];
  const float* w_hh = (const float*)d_in[2];
  const float* b_ih = (const float*)d_in[3];
  const float* b_hh = (const float*)d_in[4];
  float* out = (float*)d_out;
  char* ws = (char*)d_ws;

  const size_t o_xg  = 0;             // fp16 [400][256][2048] = 419,430,400 B
  const size_t o_xt  = 419430400;     // fp16 [400][256][256]  =  52,428,800 B
  const size_t o_wp  = 471859200;     // fp16 [2048][256]      =   1,048,576 B
  const size_t o_h   = 472907776;     // u32 [2][256][512]     =   1,048,576 B
  const size_t need  = 473956352;
  if (ws_size < need) return;

  _Float16* xg = (_Float16*)(ws + o_xg);
  u16* xt  = (u16*)(ws + o_xt);
  u16* wp  = (u16*)(ws + o_wp);
  u32* ht  = (u32*)(ws + o_h);

  hipMemsetAsync(ht, 0, 1048576, stream);  // clear stale tags (replay safety)
  hipLaunchKernelGGL(k_prep_x, dim3(51200), dim3(256), 0, stream, x, xt);
  hipLaunchKernelGGL(k_prep_w, dim3(512), dim3(256), 0, stream, w_ih, wp);
  hipLaunchKernelGGL(k_gemm_xg, dim3(12800), dim3(256), 0, stream, xt, wp, xg);
  hipLaunchKernelGGL(k_lstm, dim3(256), dim3(512), 163840, stream,
                     xg, w_hh, b_ih, b_hh, ht, out);
}